// Round 2
// 3192.583 us; speedup vs baseline: 1.6661x; 1.6661x over previous
//
#include <hip/hip_runtime.h>

typedef _Float16 f16;
typedef _Float16 f16x2 __attribute__((ext_vector_type(2)));
typedef _Float16 f16x8 __attribute__((ext_vector_type(8)));
typedef float f32x4 __attribute__((ext_vector_type(4)));
typedef unsigned long long u64;

// Problem constants: N=64, T=1024, D=512, H=512, 4H=2048, K_cat=1024
//
// ws layout (bytes):
//   x_h    : fp16 x, [64][1024][512]            = 67,108,864 @ 0
//   Wcat   : fp16 [q=2048][k=1024] (q = u*4+g)  =  4,194,304 @ 67,108,864
//   b_p    : fp32 [2048] permuted               =      8,192 @ 71,303,168
//   h16    : fp16 [2][64][512] ping-pong        =    131,072 @ 71,311,360
//   flags  : u32  [8][32] per-WG step counters  =      1,024 @ 71,442,432
#define OFF_WCAT  67108864L
#define OFF_BP    71303168L
#define OFF_H16   71311360L
#define OFF_FLAGS 71442432L

__global__ void prep_kernel(const float* __restrict__ x, const float* __restrict__ h0,
                            const float* __restrict__ Wx, const float* __restrict__ Wh,
                            const float* __restrict__ b,
                            f16* __restrict__ x_h, f16* __restrict__ Wcat,
                            float* __restrict__ b_p, f16* __restrict__ h16,
                            unsigned int* __restrict__ flags)
{
    const int tid = blockIdx.x * blockDim.x + threadIdx.x;   // 4,194,304 threads
    if (tid < 4194304) {                                     // x -> fp16, 8/thread
        const float4* src = (const float4*)x;
        float4 a = src[2*tid], c = src[2*tid + 1];
        f16x8 v;
        v[0]=(f16)a.x; v[1]=(f16)a.y; v[2]=(f16)a.z; v[3]=(f16)a.w;
        v[4]=(f16)c.x; v[5]=(f16)c.y; v[6]=(f16)c.z; v[7]=(f16)c.w;
        *(f16x8*)(x_h + (long)tid*8) = v;
    }
    // Wcat[q][k]: q = u*4 + g;  k<512 -> Wx[k][g*512+u], k>=512 -> Wh[k-512][g*512+u]
    if (tid < 2097152) {
        int q = tid >> 10, k = tid & 1023;
        int u = q >> 2, g = q & 3;
        float v = (k < 512) ? Wx[(long)k*2048 + g*512 + u]
                            : Wh[(long)(k-512)*2048 + g*512 + u];
        Wcat[tid] = (f16)v;
    }
    if (tid < 32768) h16[tid] = (f16)h0[tid];          // ping buffer 0, fp16
    if (tid < 2048)  b_p[tid] = b[(tid & 3)*512 + (tid >> 2)];
    if (tid < 256)   flags[tid] = 0u;
}

// ---- coherent memory helpers -----------------------------------------------
// All cross-WG data moves through the LLC with sc0 sc1 on both sides — the
// exact semantics __hip_atomic_{load,store}(RELAXED, AGENT) compiled to in the
// proven round-0 kernel. No fences; ordering via explicit s_waitcnt.

__device__ __forceinline__ void ld2_b128_coh(const f16* p0, const f16* p1,
                                             f16x8& v0, f16x8& v1)
{
    asm volatile("global_load_dwordx4 %0, %2, off sc0 sc1\n\t"
                 "global_load_dwordx4 %1, %3, off sc0 sc1\n\t"
                 "s_waitcnt vmcnt(0)"
                 : "=&v"(v0), "=&v"(v1) : "v"(p0), "v"(p1) : "memory");
}

__device__ __forceinline__ unsigned ld_flag(const unsigned int* p)
{
    unsigned v;
    // "=&v" early-clobber: output must NOT alias the 64-bit address pair —
    // this helper runs inside a spin loop and a clobbered address would
    // fault/hang the GPU.
    asm volatile("global_load_dword %0, %1, off sc0 sc1\n\ts_waitcnt vmcnt(0)"
                 : "=&v"(v) : "v"(p) : "memory");
    return v;
}

__device__ __forceinline__ void st_flag(unsigned int* p, unsigned v)
{
    asm volatile("global_store_dword %0, %1, off sc0 sc1" :: "v"(p), "v"(v) : "memory");
}

__device__ __forceinline__ void st_h16(f16* p, unsigned v)   // low 16 bits = half
{
    asm volatile("global_store_short %0, %1, off sc0 sc1" :: "v"(p), "v"(v) : "memory");
}

// Stage 8 rows x 512 h (fp16) from the group slab into the LDS tile.
__device__ __forceinline__ void stage_Ah16(f16* __restrict__ Ah,
                                           const f16* __restrict__ hbase, int tid)
{
    const int c0 = tid * 2, c1 = c0 + 1;        // 512 chunks of 8 halves
    f16x8 v0, v1;
    ld2_b128_coh(hbase + c0 * 8, hbase + c1 * 8, v0, v1);
    *(f16x8*)(Ah + (c0 >> 6) * 536 + (c0 & 63) * 8) = v0;
    *(f16x8*)(Ah + (c1 >> 6) * 536 + (c1 & 63) * 8) = v1;
}

// One half (K=512) of the 16x16 tile: 16 MFMAs, 4 independent partial-sum chains.
__device__ __forceinline__ void mfma_quad(const f16* A, int aoff, const f16x8* wf,
                                          f32x4& a0, f32x4& a1, f32x4& a2, f32x4& a3)
{
    #pragma unroll
    for (int kk = 0; kk < 16; kk += 4) {
        f16x8 f0 = *(const f16x8*)(A + aoff + (kk+0) * 32);
        f16x8 f1 = *(const f16x8*)(A + aoff + (kk+1) * 32);
        f16x8 f2 = *(const f16x8*)(A + aoff + (kk+2) * 32);
        f16x8 f3 = *(const f16x8*)(A + aoff + (kk+3) * 32);
        a0 = __builtin_amdgcn_mfma_f32_16x16x32_f16(f0, wf[kk+0], a0, 0, 0, 0);
        a1 = __builtin_amdgcn_mfma_f32_16x16x32_f16(f1, wf[kk+1], a1, 0, 0, 0);
        a2 = __builtin_amdgcn_mfma_f32_16x16x32_f16(f2, wf[kk+2], a2, 0, 0, 0);
        a3 = __builtin_amdgcn_mfma_f32_16x16x32_f16(f3, wf[kk+3], a3, 0, 0, 0);
    }
}

// Persistent recurrence kernel. 256 blocks x 256 threads.
// group g = blk%8, wgl = blk/8 in [0,32). Group owns batch rows [8g,8g+8).
// Wave owns 4 hidden units -> 16 gate columns = one 16x16 MFMA N-tile, K=1024.
//
// Per-step schedule (t < 1023):
//   issue x(t+1) global loads (no h dep)      <- T14 early-issue
//   h-part MFMAs (acc already holds x-part)
//   epilogue -> hval; store out + h16[nxt]
//   waitcnt(0); __syncthreads; tid0 stores flag[wgl]=t+1   (no RMW fan-in)
//   ds_write x(t+1) into Ax; __syncthreads
//   x-part MFMAs for t+1                      <- hides the flag-wait window
//   all waves poll 32 flags in parallel (one coalesced load per poll)
//   stage Ah <- h16[nxt]; __syncthreads
__global__ __launch_bounds__(256, 1) void lstm_kernel(
    const f16* __restrict__ x_h, const f16* __restrict__ Wcat,
    const float* __restrict__ b_p, f16* __restrict__ h16,
    unsigned int* __restrict__ flags, float* __restrict__ out)
{
    constexpr int AS = 536;                 // LDS row stride in halves
    __shared__ f16 Ax[8 * AS];
    __shared__ f16 Ah[8 * AS];
    __shared__ float epil[4 * 16 * 20];     // per-wave 16x20 gate transpose scratch

    const int blk  = blockIdx.x;
    const int g    = blk & 7;
    const int wgl  = blk >> 3;
    const int n0   = g * 8;
    const int tid  = threadIdx.x;
    const int wave = tid >> 6;
    const int lane = tid & 63;
    const int c    = lane & 15;             // tile column
    const int kg   = lane >> 4;             // k-group 0..3
    const int ub   = wgl * 16 + wave * 4;   // first hidden unit of this wave
    const int q0   = ub * 4;                // first gate column

    // Weight B-fragments resident in registers for the whole kernel.
    f16x8 wfrag[32];
    {
        const f16* wp = Wcat + (long)(q0 + c) * 1024 + kg * 8;
        #pragma unroll
        for (int kk = 0; kk < 32; ++kk)
            wfrag[kk] = *(const f16x8*)(wp + kk * 32);
    }
    const float bias = b_p[q0 + c];

    const int aoff = (lane & 7) * AS + kg * 8;
    float* ep = epil + wave * 320;
    const int rb = lane >> 4;
    const int er = lane >> 2;               // batch row 0..7 (epilogue)
    const int eu = lane & 3;                // unit-local 0..3
    float cst = 0.f;
    unsigned int* myflags = flags + g * 32;
    int cur = 0;

    // x(t+1) prefetch addressing: thread covers chunks tid and tid+256
    const int pr0 = tid >> 6, pch = tid & 63;
    const f16* xb0 = x_h + ((long)(n0 + pr0)     * 1024) * 512 + pch * 8;
    const f16* xb1 = x_h + ((long)(n0 + pr0 + 4) * 1024) * 512 + pch * 8;
    f16* axd0 = Ax + pr0       * AS + pch * 8;
    f16* axd1 = Ax + (pr0 + 4) * AS + pch * 8;

    // ---- prologue: stage x_0 and h_0, then x-part of t=0 ----
    *(f16x8*)axd0 = *(const f16x8*)(xb0);
    *(f16x8*)axd1 = *(const f16x8*)(xb1);
    stage_Ah16(Ah, h16 + n0 * 512, tid);
    __syncthreads();

    f32x4 a0 = {0.f,0.f,0.f,0.f}, a1 = {0.f,0.f,0.f,0.f};
    f32x4 a2 = {0.f,0.f,0.f,0.f}, a3 = {0.f,0.f,0.f,0.f};
    mfma_quad(Ax, aoff, wfrag, a0, a1, a2, a3);          // x part, t=0

    for (int t = 0; t < 1024; ++t) {
        // early-issue next x tile (pure global loads, no dependence on h)
        f16x8 xv0, xv1;
        if (t < 1023) {
            xv0 = *(const f16x8*)(xb0 + (long)(t + 1) * 512);
            xv1 = *(const f16x8*)(xb1 + (long)(t + 1) * 512);
        }

        // ---- h-part MFMAs: acc += h_t @ Wh_tile ----
        mfma_quad(Ah, aoff, wfrag + 16, a0, a1, a2, a3);

        // ---- gate transpose via per-wave LDS (same-wave DS is in-order) ----
        #pragma unroll
        for (int j = 0; j < 4; ++j) {
            float av = ((a0[j] + a1[j]) + (a2[j] + a3[j])) + bias;
            ep[(rb * 4 + j) * 20 + c] = av;
        }

        const int nxt = cur ^ 1;
        if (lane < 32) {
            float4 g4 = *(const float4*)(ep + er * 20 + eu * 4);   // i,f,o,g
            float iv = 1.f / (1.f + __expf(-g4.x));
            float fv = 1.f / (1.f + __expf(-g4.y));
            float ov = 1.f / (1.f + __expf(-g4.z));
            float gv = 2.f / (1.f + __expf(-2.f * g4.w)) - 1.f;    // tanh
            float cn = fv * cst + iv * gv;
            cst = cn;
            float th = 2.f / (1.f + __expf(-2.f * cn)) - 1.f;      // tanh
            float hval = ov * th;
            const int n = n0 + er;
            const int u = ub + eu;
            out[((long)n * 1024 + t) * 512 + u] = hval;
            if (t < 1023) {
                union { f16 h; unsigned short s; } cv; cv.h = (f16)hval;
                st_h16(h16 + (long)nxt * 32768 + n * 512 + u, (unsigned)cv.s);
            }
        }

        if (t < 1023) {
            // release: drain my h16 stores (and x prefetch loads), then
            // barrier so ALL waves of this WG are drained, then one flag store.
            asm volatile("s_waitcnt vmcnt(0)" ::: "memory");
            __syncthreads();                 // all waves drained; Ax/Ah reads done
            if (tid == 0) st_flag(myflags + wgl, (unsigned)(t + 1));

            // restage x_{t+1} from prefetched registers
            *(f16x8*)axd0 = xv0;
            *(f16x8*)axd1 = xv1;
            __syncthreads();

            // x-part MFMAs for t+1 -- hides the flag-wait window
            a0 = (f32x4){0.f,0.f,0.f,0.f}; a1 = (f32x4){0.f,0.f,0.f,0.f};
            a2 = (f32x4){0.f,0.f,0.f,0.f}; a3 = (f32x4){0.f,0.f,0.f,0.f};
            mfma_quad(Ax, aoff, wfrag, a0, a1, a2, a3);

            // acquire: every wave polls all 32 group flags in parallel
            const unsigned tgt = (unsigned)(t + 1);
            const unsigned int* fp = myflags + (lane & 31);
            while (true) {
                unsigned f = ld_flag(fp);
                if (__all((int)(f >= tgt))) break;
            }

            // stage h_{t+1}
            stage_Ah16(Ah, h16 + (long)nxt * 32768 + n0 * 512, tid);
            __syncthreads();
            cur = nxt;
        }
    }
}

extern "C" void kernel_launch(void* const* d_in, const int* in_sizes, int n_in,
                              void* d_out, int out_size, void* d_ws, size_t ws_size,
                              hipStream_t stream)
{
    const float* x  = (const float*)d_in[0];
    const float* h0 = (const float*)d_in[1];
    const float* Wx = (const float*)d_in[2];
    const float* Wh = (const float*)d_in[3];
    const float* b  = (const float*)d_in[4];
    float* out = (float*)d_out;

    char* ws = (char*)d_ws;
    f16*   x_h    = (f16*)(ws);
    f16*   Wcat   = (f16*)(ws + OFF_WCAT);
    float* b_p    = (float*)(ws + OFF_BP);
    f16*   h16    = (f16*)(ws + OFF_H16);
    unsigned int* flags  = (unsigned int*)(ws + OFF_FLAGS);

    prep_kernel<<<16384, 256, 0, stream>>>(x, h0, Wx, Wh, b, x_h, Wcat, b_p, h16, flags);
    lstm_kernel<<<256, 256, 0, stream>>>(x_h, Wcat, b_p, h16, flags, out);
}

// Round 4
// 2239.019 us; speedup vs baseline: 2.3757x; 1.4259x over previous
//
#include <hip/hip_runtime.h>

typedef _Float16 f16;
typedef _Float16 f16x2 __attribute__((ext_vector_type(2)));
typedef _Float16 f16x8 __attribute__((ext_vector_type(8)));
typedef float f32x4 __attribute__((ext_vector_type(4)));
typedef unsigned int u32;
typedef u32 u32x4 __attribute__((ext_vector_type(4)));

// Problem constants: N=64, T=1024, D=512, H=512, 4H=2048, K_cat=1024
//
// ws layout (bytes):
//   x_h    : fp16 x, [64][1024][512]            = 67,108,864 @ 0
//   Wcat   : fp16 [q=2048][k=1024] (q = u*4+g)  =  4,194,304 @ 67,108,864
//   b_p    : fp32 [2048] permuted               =      8,192 @ 71,303,168
//   h32    : u32  [2][64][512] tagged ping-pong = (tag<<16)|fp16(h)
//                                               =    262,144 @ 71,311,360
#define OFF_WCAT  67108864L
#define OFF_BP    71303168L
#define OFF_H32   71311360L

constexpr int AS = 536;                 // LDS row stride in halves

__global__ void prep_kernel(const float* __restrict__ x, const float* __restrict__ h0,
                            const float* __restrict__ Wx, const float* __restrict__ Wh,
                            const float* __restrict__ b,
                            f16* __restrict__ x_h, f16* __restrict__ Wcat,
                            float* __restrict__ b_p, u32* __restrict__ h32)
{
    const int tid = blockIdx.x * blockDim.x + threadIdx.x;   // 4,194,304 threads
    if (tid < 4194304) {                                     // x -> fp16, 8/thread
        const float4* src = (const float4*)x;
        float4 a = src[2*tid], c = src[2*tid + 1];
        f16x8 v;
        v[0]=(f16)a.x; v[1]=(f16)a.y; v[2]=(f16)a.z; v[3]=(f16)a.w;
        v[4]=(f16)c.x; v[5]=(f16)c.y; v[6]=(f16)c.z; v[7]=(f16)c.w;
        *(f16x8*)(x_h + (long)tid*8) = v;
    }
    // Wcat[q][k]: q = u*4 + g;  k<512 -> Wx[k][g*512+u], k>=512 -> Wh[k-512][g*512+u]
    if (tid < 2097152) {
        int q = tid >> 10, k = tid & 1023;
        int u = q >> 2, g = q & 3;
        float v = (k < 512) ? Wx[(long)k*2048 + g*512 + u]
                            : Wh[(long)(k-512)*2048 + g*512 + u];
        Wcat[tid] = (f16)v;
    }
    if (tid < 32768) {
        union { f16 h; unsigned short s; } cv; cv.h = (f16)h0[tid];
        h32[tid]         = (u32)cv.s;        // buffer 0: tag 0 | h0
        h32[32768 + tid] = 0xFFFF0000u;      // buffer 1: invalid tag (never matches)
    }
    if (tid < 2048)  b_p[tid] = b[(tid & 3)*512 + (tid >> 2)];
}

// ---- coherent memory helpers (LLC path, sc0 sc1 — proven rounds 0/2) -------
// "=&v" early-clobber everywhere: outputs must never alias the 64-bit address
// pairs (a clobbered address inside the poll loop faults the GPU).

__device__ __forceinline__ void ld16_coh(const u32* p, u32x4& a, u32x4& b,
                                         u32x4& c, u32x4& d)
{
    asm volatile("global_load_dwordx4 %0, %4, off sc0 sc1\n\t"
                 "global_load_dwordx4 %1, %5, off sc0 sc1\n\t"
                 "global_load_dwordx4 %2, %6, off sc0 sc1\n\t"
                 "global_load_dwordx4 %3, %7, off sc0 sc1\n\t"
                 "s_waitcnt vmcnt(0)"
                 : "=&v"(a), "=&v"(b), "=&v"(c), "=&v"(d)
                 : "v"(p), "v"(p + 4), "v"(p + 8), "v"(p + 12)
                 : "memory");
}

__device__ __forceinline__ void st_w32(u32* p, unsigned v)
{
    asm volatile("global_store_dword %0, %1, off sc0 sc1" :: "v"(p), "v"(v) : "memory");
}

// Poll this thread's 16 tagged h-words until all tags == tgt, then pack the
// fp16 payloads into the LDS Ah tile. Tag+value arrive atomically per dword,
// so no flags and no producer-side store drain are needed.
__device__ __forceinline__ void poll_stage(f16* __restrict__ Ah,
                                           const u32* __restrict__ wbase,
                                           unsigned tgt, int tid)
{
    const u32* p = wbase + tid * 16;
    u32x4 A, B, C, D;
    while (true) {
        ld16_coh(p, A, B, C, D);
        unsigned m;
        m  = (A.x>>16)^tgt; m |= (A.y>>16)^tgt; m |= (A.z>>16)^tgt; m |= (A.w>>16)^tgt;
        m |= (B.x>>16)^tgt; m |= (B.y>>16)^tgt; m |= (B.z>>16)^tgt; m |= (B.w>>16)^tgt;
        m |= (C.x>>16)^tgt; m |= (C.y>>16)^tgt; m |= (C.z>>16)^tgt; m |= (C.w>>16)^tgt;
        m |= (D.x>>16)^tgt; m |= (D.y>>16)^tgt; m |= (D.z>>16)^tgt; m |= (D.w>>16)^tgt;
        if (m == 0) break;
    }
    u32x4 lo, hi;
    lo.x = (A.x & 0xFFFFu) | (A.y << 16); lo.y = (A.z & 0xFFFFu) | (A.w << 16);
    lo.z = (B.x & 0xFFFFu) | (B.y << 16); lo.w = (B.z & 0xFFFFu) | (B.w << 16);
    hi.x = (C.x & 0xFFFFu) | (C.y << 16); hi.y = (C.z & 0xFFFFu) | (C.w << 16);
    hi.z = (D.x & 0xFFFFu) | (D.y << 16); hi.w = (D.z & 0xFFFFu) | (D.w << 16);
    const int row = tid >> 5;               // 32 threads per 512-col row
    const int col = (tid & 31) * 16;
    u32* dst = (u32*)(Ah + row * AS + col);
    *(u32x4*)dst       = lo;
    *(u32x4*)(dst + 4) = hi;
}

// One half (K=512) of the 16x16 tile: 16 MFMAs, 4 independent partial-sum chains.
__device__ __forceinline__ void mfma_quad(const f16* A, int aoff, const f16x8* wf,
                                          f32x4& a0, f32x4& a1, f32x4& a2, f32x4& a3)
{
    #pragma unroll
    for (int kk = 0; kk < 16; kk += 4) {
        f16x8 f0 = *(const f16x8*)(A + aoff + (kk+0) * 32);
        f16x8 f1 = *(const f16x8*)(A + aoff + (kk+1) * 32);
        f16x8 f2 = *(const f16x8*)(A + aoff + (kk+2) * 32);
        f16x8 f3 = *(const f16x8*)(A + aoff + (kk+3) * 32);
        a0 = __builtin_amdgcn_mfma_f32_16x16x32_f16(f0, wf[kk+0], a0, 0, 0, 0);
        a1 = __builtin_amdgcn_mfma_f32_16x16x32_f16(f1, wf[kk+1], a1, 0, 0, 0);
        a2 = __builtin_amdgcn_mfma_f32_16x16x32_f16(f2, wf[kk+2], a2, 0, 0, 0);
        a3 = __builtin_amdgcn_mfma_f32_16x16x32_f16(f3, wf[kk+3], a3, 0, 0, 0);
    }
}

// light workgroup barrier: orders LDS only; leaves global stores/loads in
// flight (avoids the compiler's vmcnt(0) drain inside __syncthreads).
__device__ __forceinline__ void bar_lds()
{
    asm volatile("s_waitcnt lgkmcnt(0)" ::: "memory");
    __builtin_amdgcn_s_barrier();
}

// Persistent recurrence kernel. 256 blocks x 256 threads.
// group g = blk%8, wgl = blk/8 in [0,32). Group owns batch rows [8g,8g+8).
// Wave owns 4 hidden units -> 16 gate columns = one 16x16 MFMA N-tile, K=1024.
//
// Per-step schedule (t < 1023):
//   issue x(t+1) global loads (no h dep)
//   h-part MFMAs (acc already holds x-part)
//   epilogue -> hval; store out + tagged h32[nxt] (fire, no drain)
//   bar_lds; restage x(t+1) into Ax; bar_lds
//   x-part MFMAs for t+1                       <- hides producer->LLC latency
//   poll own 16 tagged h-words until tag==t+1; pack -> Ah; bar_lds
__global__ __launch_bounds__(256, 1) void lstm_kernel(
    const f16* __restrict__ x_h, const f16* __restrict__ Wcat,
    const float* __restrict__ b_p, u32* __restrict__ h32,
    float* __restrict__ out)
{
    __shared__ f16 Ax[8 * AS];
    __shared__ f16 Ah[8 * AS];
    __shared__ float epil[4 * 16 * 20];     // per-wave 16x20 gate transpose scratch

    const int blk  = blockIdx.x;
    const int g    = blk & 7;
    const int wgl  = blk >> 3;
    const int n0   = g * 8;
    const int tid  = threadIdx.x;
    const int wave = tid >> 6;
    const int lane = tid & 63;
    const int c    = lane & 15;             // tile column
    const int kg   = lane >> 4;             // k-group 0..3
    const int ub   = wgl * 16 + wave * 4;   // first hidden unit of this wave
    const int q0   = ub * 4;                // first gate column

    // Weight B-fragments resident in registers for the whole kernel.
    f16x8 wfrag[32];
    {
        const f16* wp = Wcat + (long)(q0 + c) * 1024 + kg * 8;
        #pragma unroll
        for (int kk = 0; kk < 32; ++kk)
            wfrag[kk] = *(const f16x8*)(wp + kk * 32);
    }
    const float bias = b_p[q0 + c];

    const int aoff = (lane & 7) * AS + kg * 8;
    float* ep = epil + wave * 320;
    const int rb = lane >> 4;
    const int er = lane >> 2;               // batch row 0..7 (epilogue)
    const int eu = lane & 3;                // unit-local 0..3
    float cst = 0.f;
    int cur = 0;

    // x(t+1) prefetch addressing: thread covers chunks tid and tid+256
    const int pr0 = tid >> 6, pch = tid & 63;
    const f16* xb0 = x_h + ((long)(n0 + pr0)     * 1024) * 512 + pch * 8;
    const f16* xb1 = x_h + ((long)(n0 + pr0 + 4) * 1024) * 512 + pch * 8;
    f16* axd0 = Ax + pr0       * AS + pch * 8;
    f16* axd1 = Ax + (pr0 + 4) * AS + pch * 8;

    // group h-word slab bases (4096 words each)
    u32* hb0 = h32 + n0 * 512;              // buffer 0
    u32* hb1 = h32 + 32768 + n0 * 512;      // buffer 1

    // ---- prologue: stage x_0 and h_0, then x-part of t=0 ----
    *(f16x8*)axd0 = *(const f16x8*)(xb0);
    *(f16x8*)axd1 = *(const f16x8*)(xb1);
    poll_stage(Ah, hb0, 0u, tid);           // prep wrote tag 0; succeeds first try
    __syncthreads();

    f32x4 a0 = {0.f,0.f,0.f,0.f}, a1 = {0.f,0.f,0.f,0.f};
    f32x4 a2 = {0.f,0.f,0.f,0.f}, a3 = {0.f,0.f,0.f,0.f};
    mfma_quad(Ax, aoff, wfrag, a0, a1, a2, a3);          // x part, t=0

    for (int t = 0; t < 1024; ++t) {
        // early-issue next x tile (pure global loads, no dependence on h)
        f16x8 xv0, xv1;
        if (t < 1023) {
            xv0 = *(const f16x8*)(xb0 + (long)(t + 1) * 512);
            xv1 = *(const f16x8*)(xb1 + (long)(t + 1) * 512);
        }

        // ---- h-part MFMAs: acc += h_t @ Wh_tile ----
        mfma_quad(Ah, aoff, wfrag + 16, a0, a1, a2, a3);

        // ---- gate transpose via per-wave LDS (same-wave DS is in-order) ----
        #pragma unroll
        for (int j = 0; j < 4; ++j) {
            float av = ((a0[j] + a1[j]) + (a2[j] + a3[j])) + bias;
            ep[(rb * 4 + j) * 20 + c] = av;
        }

        const int nxt = cur ^ 1;
        if (lane < 32) {
            float4 g4 = *(const float4*)(ep + er * 20 + eu * 4);   // i,f,o,g
            float iv = 1.f / (1.f + __expf(-g4.x));
            float fv = 1.f / (1.f + __expf(-g4.y));
            float ov = 1.f / (1.f + __expf(-g4.z));
            float gv = 2.f / (1.f + __expf(-2.f * g4.w)) - 1.f;    // tanh
            float cn = fv * cst + iv * gv;
            cst = cn;
            float th = 2.f / (1.f + __expf(-2.f * cn)) - 1.f;      // tanh
            float hval = ov * th;
            const int n = n0 + er;
            const int u = ub + eu;
            out[((long)n * 1024 + t) * 512 + u] = hval;
            if (t < 1023) {
                union { f16 h; unsigned short s; } cv; cv.h = (f16)hval;
                unsigned w = ((unsigned)(t + 1) << 16) | (unsigned)cv.s;
                st_w32((nxt ? hb1 : hb0) + (n - n0) * 512 + u, w);  // fire & forget
            }
        }

        if (t < 1023) {
            // all waves done reading Ax/Ah this step (LDS ordering only;
            // h32 stores and x loads remain in flight)
            bar_lds();

            // restage x_{t+1} from prefetched registers
            *(f16x8*)axd0 = xv0;
            *(f16x8*)axd1 = xv1;
            bar_lds();

            // x-part MFMAs for t+1 -- overlaps producers' store->LLC latency
            a0 = (f32x4){0.f,0.f,0.f,0.f}; a1 = (f32x4){0.f,0.f,0.f,0.f};
            a2 = (f32x4){0.f,0.f,0.f,0.f}; a3 = (f32x4){0.f,0.f,0.f,0.f};
            mfma_quad(Ax, aoff, wfrag, a0, a1, a2, a3);

            // acquire + stage in one step: poll own tagged h-words directly
            poll_stage(Ah, nxt ? hb1 : hb0, (unsigned)(t + 1), tid);
            bar_lds();
            cur = nxt;
        }
    }
}

extern "C" void kernel_launch(void* const* d_in, const int* in_sizes, int n_in,
                              void* d_out, int out_size, void* d_ws, size_t ws_size,
                              hipStream_t stream)
{
    const float* x  = (const float*)d_in[0];
    const float* h0 = (const float*)d_in[1];
    const float* Wx = (const float*)d_in[2];
    const float* Wh = (const float*)d_in[3];
    const float* b  = (const float*)d_in[4];
    float* out = (float*)d_out;

    char* ws = (char*)d_ws;
    f16*   x_h  = (f16*)(ws);
    f16*   Wcat = (f16*)(ws + OFF_WCAT);
    float* b_p  = (float*)(ws + OFF_BP);
    u32*   h32  = (u32*)(ws + OFF_H32);

    prep_kernel<<<16384, 256, 0, stream>>>(x, h0, Wx, Wh, b, x_h, Wcat, b_p, h32);
    lstm_kernel<<<256, 256, 0, stream>>>(x_h, Wcat, b_p, h32, out);
}